// Round 3
// baseline (1168.648 us; speedup 1.0000x reference)
//
#include <hip/hip_runtime.h>

#define NBLK 256

// tanh(x) = 1 - 2/(exp(2x)+1); exp(2x) = exp2(x * 2*log2(e)).
// Overflow -> inf -> rcp(inf)=0 -> 1; underflow -> -1. abs err ~3e-7.
__device__ __forceinline__ float fast_tanh(float x) {
    float e = __builtin_amdgcn_exp2f(x * 2.885390082f);
    return 1.0f - 2.0f * __builtin_amdgcn_rcpf(e + 1.0f);
}

// One hidden layer: (nh, ndh) = tanh-prop of (h, dh) through W[L], b[L].
// sW4: [L][k][jj] float4, linear L*100 + k*5 + jj.  sB4: [L][jj], linear L*5+jj.
template <int L>
__device__ __forceinline__ void layer(const float4* __restrict__ sW4,
                                      const float4* __restrict__ sB4,
                                      const float (&h)[20], const float (&dh)[20],
                                      float (&nh)[20], float (&ndh)[20]) {
#pragma unroll
    for (int jj = 0; jj < 5; ++jj) {
        const float4 b = sB4[L * 5 + jj];
        float a0 = b.x, a1 = b.y, a2 = b.z, a3 = b.w;
        float d0 = 0.f, d1 = 0.f, d2 = 0.f, d3 = 0.f;
#pragma unroll
        for (int k = 0; k < 20; ++k) {
            const float4 ww = sW4[L * 100 + k * 5 + jj];
            const float hk = h[k], dk = dh[k];
            a0 += hk * ww.x; a1 += hk * ww.y; a2 += hk * ww.z; a3 += hk * ww.w;
            d0 += dk * ww.x; d1 += dk * ww.y; d2 += dk * ww.z; d3 += dk * ww.w;
        }
        const float e0 = fast_tanh(a0), e1 = fast_tanh(a1),
                    e2 = fast_tanh(a2), e3 = fast_tanh(a3);
        nh[jj * 4 + 0] = e0; nh[jj * 4 + 1] = e1;
        nh[jj * 4 + 2] = e2; nh[jj * 4 + 3] = e3;
        ndh[jj * 4 + 0] = (1.0f - e0 * e0) * d0;
        ndh[jj * 4 + 1] = (1.0f - e1 * e1) * d1;
        ndh[jj * 4 + 2] = (1.0f - e2 * e2) * d2;
        ndh[jj * 4 + 3] = (1.0f - e3 * e3) * d3;
    }
}

__global__ __launch_bounds__(NBLK, 6) void pinn_kernel(
    const float* __restrict__ T,
    const float* __restrict__ W1, const float* __restrict__ b1,
    const float* __restrict__ W2, const float* __restrict__ b2,
    const float* __restrict__ W3, const float* __restrict__ b3,
    const float* __restrict__ W4, const float* __restrict__ b4,
    const float* __restrict__ Wo, const float* __restrict__ bo,
    const float* __restrict__ C1, const float* __restrict__ C2, const float* __restrict__ C3,
    float* __restrict__ out, int n)
{
    __shared__ float4 sW4[300];    // W2,W3,W4: [L][k][jj]
    __shared__ float4 sB4[15];     // b2,b3,b4: [L][jj]
    __shared__ float4 sW1v[5];     // W1 (20 floats)
    __shared__ float4 sb1v[5];     // b1
    __shared__ float4 sWoT4[15];   // Wo transposed: [o][k] 3x20
    __shared__ float  sbo[3];

    const int tid = threadIdx.x;
    // ---- staging: grid-stride so ALL 300 float4s are covered by 256 threads ----
    for (int v = tid; v < 300; v += NBLK) {
        float4 val;
        if (v < 100)      val = ((const float4*)W2)[v];
        else if (v < 200) val = ((const float4*)W3)[v - 100];
        else              val = ((const float4*)W4)[v - 200];
        sW4[v] = val;
    }
    if (tid < 5) {
        sB4[tid]      = ((const float4*)b2)[tid];
        sB4[5 + tid]  = ((const float4*)b3)[tid];
        sB4[10 + tid] = ((const float4*)b4)[tid];
        sW1v[tid]     = ((const float4*)W1)[tid];
        sb1v[tid]     = ((const float4*)b1)[tid];
    }
    if (tid < 60) {
        // sWoT[o][k] = Wo[k][o]
        reinterpret_cast<float*>(sWoT4)[(tid % 3) * 20 + (tid / 3)] = Wo[tid];
    }
    if (tid < 3) sbo[tid] = bo[tid];

    const int i = blockIdx.x * NBLK + tid;
    const float t = (i < n) ? T[i] : 0.0f;   // load before barrier to hide latency
    __syncthreads();
    if (i >= n) return;

    float hA[20], dA[20], hB[20], dB[20];

    // ---- layer 1: z = t*W1 + b1, dz = W1 ----
#pragma unroll
    for (int jj = 0; jj < 5; ++jj) {
        const float4 w = sW1v[jj];
        const float4 b = sb1v[jj];
        const float z0 = t * w.x + b.x, z1 = t * w.y + b.y,
                    z2 = t * w.z + b.z, z3 = t * w.w + b.w;
        const float e0 = fast_tanh(z0), e1 = fast_tanh(z1),
                    e2 = fast_tanh(z2), e3 = fast_tanh(z3);
        hA[jj * 4 + 0] = e0; hA[jj * 4 + 1] = e1;
        hA[jj * 4 + 2] = e2; hA[jj * 4 + 3] = e3;
        dA[jj * 4 + 0] = (1.0f - e0 * e0) * w.x;
        dA[jj * 4 + 1] = (1.0f - e1 * e1) * w.y;
        dA[jj * 4 + 2] = (1.0f - e2 * e2) * w.z;
        dA[jj * 4 + 3] = (1.0f - e3 * e3) * w.w;
    }

    // ---- layers 2..4, fully unrolled, alternating register arrays ----
    layer<0>(sW4, sB4, hA, dA, hB, dB);
    layer<1>(sW4, sB4, hB, dB, hA, dA);
    layer<2>(sW4, sB4, hA, dA, hB, dB);

    // ---- output layer ----
    float o[3], dO[3];
#pragma unroll
    for (int j = 0; j < 3; ++j) {
        float a = sbo[j], d = 0.f;
#pragma unroll
        for (int kk = 0; kk < 5; ++kk) {
            const float4 ww = sWoT4[j * 5 + kk];
            const int k = kk * 4;
            a += hB[k] * ww.x + hB[k + 1] * ww.y + hB[k + 2] * ww.z + hB[k + 3] * ww.w;
            d += dB[k] * ww.x + dB[k + 1] * ww.y + dB[k + 2] * ww.z + dB[k + 3] * ww.w;
        }
        o[j] = a; dO[j] = d;
    }

    const float x = o[0], y = o[1], zz = o[2];
    const float dx = dO[0], dy = dO[1], dz = dO[2];
    const float c1 = C1[0], c2 = C2[0], c3 = C3[0];

    const float fx = dx - c1 * (y - x);
    const float fy = dy - x * (c2 - zz) + y;
    const float fz = dz - x * y + c3 * zz;

    float2* po = reinterpret_cast<float2*>(out + (size_t)i * 6);
    po[0] = make_float2(x,  y);
    po[1] = make_float2(zz, fx);
    po[2] = make_float2(fy, fz);
}

extern "C" void kernel_launch(void* const* d_in, const int* in_sizes, int n_in,
                              void* d_out, int out_size, void* d_ws, size_t ws_size,
                              hipStream_t stream) {
    const float* T  = (const float*)d_in[0];
    const float* W1 = (const float*)d_in[1];
    const float* b1 = (const float*)d_in[2];
    const float* W2 = (const float*)d_in[3];
    const float* b2 = (const float*)d_in[4];
    const float* W3 = (const float*)d_in[5];
    const float* b3 = (const float*)d_in[6];
    const float* W4 = (const float*)d_in[7];
    const float* b4 = (const float*)d_in[8];
    const float* Wo = (const float*)d_in[9];
    const float* bo = (const float*)d_in[10];
    const float* C1 = (const float*)d_in[11];
    const float* C2 = (const float*)d_in[12];
    const float* C3 = (const float*)d_in[13];
    float* out = (float*)d_out;

    const int n = in_sizes[0];
    const int blocks = (n + NBLK - 1) / NBLK;
    pinn_kernel<<<blocks, NBLK, 0, stream>>>(T, W1, b1, W2, b2, W3, b3, W4, b4,
                                             Wo, bo, C1, C2, C3, out, n);
}

// Round 4
// 286.025 us; speedup vs baseline: 4.0858x; 4.0858x over previous
//
#include <hip/hip_runtime.h>

#define NBLK 256

// tanh(x) = 1 - 2/(exp(2x)+1); exp(2x) = exp2(x * 2*log2(e)).
// Overflow -> inf -> rcp(inf)=0 -> 1; underflow -> -1. abs err ~3e-7.
__device__ __forceinline__ float fast_tanh(float x) {
    float e = __builtin_amdgcn_exp2f(x * 2.885390082f);
    return 1.0f - 2.0f * __builtin_amdgcn_rcpf(e + 1.0f);
}

// One hidden layer: (nh, ndh) = tanh-prop of (h, dh) through W[L], b[L].
// sW4: [L][k][jj] float4, linear L*100 + k*5 + jj.  sB4: [L][jj], linear L*5+jj.
template <int L>
__device__ __forceinline__ void layer(const float4* __restrict__ sW4,
                                      const float4* __restrict__ sB4,
                                      const float (&h)[20], const float (&dh)[20],
                                      float (&nh)[20], float (&ndh)[20]) {
#pragma unroll
    for (int jj = 0; jj < 5; ++jj) {
        const float4 b = sB4[L * 5 + jj];
        float a0 = b.x, a1 = b.y, a2 = b.z, a3 = b.w;
        float d0 = 0.f, d1 = 0.f, d2 = 0.f, d3 = 0.f;
#pragma unroll
        for (int k = 0; k < 20; ++k) {
            const float4 ww = sW4[L * 100 + k * 5 + jj];
            const float hk = h[k], dk = dh[k];
            a0 += hk * ww.x; a1 += hk * ww.y; a2 += hk * ww.z; a3 += hk * ww.w;
            d0 += dk * ww.x; d1 += dk * ww.y; d2 += dk * ww.z; d3 += dk * ww.w;
        }
        const float e0 = fast_tanh(a0), e1 = fast_tanh(a1),
                    e2 = fast_tanh(a2), e3 = fast_tanh(a3);
        nh[jj * 4 + 0] = e0; nh[jj * 4 + 1] = e1;
        nh[jj * 4 + 2] = e2; nh[jj * 4 + 3] = e3;
        ndh[jj * 4 + 0] = (1.0f - e0 * e0) * d0;
        ndh[jj * 4 + 1] = (1.0f - e1 * e1) * d1;
        ndh[jj * 4 + 2] = (1.0f - e2 * e2) * d2;
        ndh[jj * 4 + 3] = (1.0f - e3 * e3) * d3;
    }
}

// launch_bounds(256, 4): VGPR cap 128. (256,6) capped at ~85 and spilled the
// unrolled h/dh state to scratch -> 4.26 GB HBM traffic, 10x regression (R3).
__global__ __launch_bounds__(NBLK, 4) void pinn_kernel(
    const float* __restrict__ T,
    const float* __restrict__ W1, const float* __restrict__ b1,
    const float* __restrict__ W2, const float* __restrict__ b2,
    const float* __restrict__ W3, const float* __restrict__ b3,
    const float* __restrict__ W4, const float* __restrict__ b4,
    const float* __restrict__ Wo, const float* __restrict__ bo,
    const float* __restrict__ C1, const float* __restrict__ C2, const float* __restrict__ C3,
    float* __restrict__ out, int n)
{
    __shared__ float4 sW4[300];    // W2,W3,W4: [L][k][jj]
    __shared__ float4 sB4[15];     // b2,b3,b4: [L][jj]
    __shared__ float4 sW1v[5];     // W1 (20 floats)
    __shared__ float4 sb1v[5];     // b1
    __shared__ float4 sWoT4[15];   // Wo transposed: [o][k] 3x20
    __shared__ float  sbo[3];

    const int tid = threadIdx.x;
    // ---- staging: grid-stride so ALL 300 float4s are covered by 256 threads ----
    for (int v = tid; v < 300; v += NBLK) {
        float4 val;
        if (v < 100)      val = ((const float4*)W2)[v];
        else if (v < 200) val = ((const float4*)W3)[v - 100];
        else              val = ((const float4*)W4)[v - 200];
        sW4[v] = val;
    }
    if (tid < 5) {
        sB4[tid]      = ((const float4*)b2)[tid];
        sB4[5 + tid]  = ((const float4*)b3)[tid];
        sB4[10 + tid] = ((const float4*)b4)[tid];
        sW1v[tid]     = ((const float4*)W1)[tid];
        sb1v[tid]     = ((const float4*)b1)[tid];
    }
    if (tid < 60) {
        // sWoT[o][k] = Wo[k][o]
        reinterpret_cast<float*>(sWoT4)[(tid % 3) * 20 + (tid / 3)] = Wo[tid];
    }
    if (tid < 3) sbo[tid] = bo[tid];

    const int i = blockIdx.x * NBLK + tid;
    const float t = (i < n) ? T[i] : 0.0f;   // load before barrier to hide latency
    __syncthreads();
    if (i >= n) return;

    float hA[20], dA[20], hB[20], dB[20];

    // ---- layer 1: z = t*W1 + b1, dz = W1 ----
#pragma unroll
    for (int jj = 0; jj < 5; ++jj) {
        const float4 w = sW1v[jj];
        const float4 b = sb1v[jj];
        const float z0 = t * w.x + b.x, z1 = t * w.y + b.y,
                    z2 = t * w.z + b.z, z3 = t * w.w + b.w;
        const float e0 = fast_tanh(z0), e1 = fast_tanh(z1),
                    e2 = fast_tanh(z2), e3 = fast_tanh(z3);
        hA[jj * 4 + 0] = e0; hA[jj * 4 + 1] = e1;
        hA[jj * 4 + 2] = e2; hA[jj * 4 + 3] = e3;
        dA[jj * 4 + 0] = (1.0f - e0 * e0) * w.x;
        dA[jj * 4 + 1] = (1.0f - e1 * e1) * w.y;
        dA[jj * 4 + 2] = (1.0f - e2 * e2) * w.z;
        dA[jj * 4 + 3] = (1.0f - e3 * e3) * w.w;
    }

    // ---- layers 2..4, fully unrolled, alternating register arrays ----
    layer<0>(sW4, sB4, hA, dA, hB, dB);
    layer<1>(sW4, sB4, hB, dB, hA, dA);
    layer<2>(sW4, sB4, hA, dA, hB, dB);

    // ---- output layer ----
    float o[3], dO[3];
#pragma unroll
    for (int j = 0; j < 3; ++j) {
        float a = sbo[j], d = 0.f;
#pragma unroll
        for (int kk = 0; kk < 5; ++kk) {
            const float4 ww = sWoT4[j * 5 + kk];
            const int k = kk * 4;
            a += hB[k] * ww.x + hB[k + 1] * ww.y + hB[k + 2] * ww.z + hB[k + 3] * ww.w;
            d += dB[k] * ww.x + dB[k + 1] * ww.y + dB[k + 2] * ww.z + dB[k + 3] * ww.w;
        }
        o[j] = a; dO[j] = d;
    }

    const float x = o[0], y = o[1], zz = o[2];
    const float dx = dO[0], dy = dO[1], dz = dO[2];
    const float c1 = C1[0], c2 = C2[0], c3 = C3[0];

    const float fx = dx - c1 * (y - x);
    const float fy = dy - x * (c2 - zz) + y;
    const float fz = dz - x * y + c3 * zz;

    float2* po = reinterpret_cast<float2*>(out + (size_t)i * 6);
    po[0] = make_float2(x,  y);
    po[1] = make_float2(zz, fx);
    po[2] = make_float2(fy, fz);
}

extern "C" void kernel_launch(void* const* d_in, const int* in_sizes, int n_in,
                              void* d_out, int out_size, void* d_ws, size_t ws_size,
                              hipStream_t stream) {
    const float* T  = (const float*)d_in[0];
    const float* W1 = (const float*)d_in[1];
    const float* b1 = (const float*)d_in[2];
    const float* W2 = (const float*)d_in[3];
    const float* b2 = (const float*)d_in[4];
    const float* W3 = (const float*)d_in[5];
    const float* b3 = (const float*)d_in[6];
    const float* W4 = (const float*)d_in[7];
    const float* b4 = (const float*)d_in[8];
    const float* Wo = (const float*)d_in[9];
    const float* bo = (const float*)d_in[10];
    const float* C1 = (const float*)d_in[11];
    const float* C2 = (const float*)d_in[12];
    const float* C3 = (const float*)d_in[13];
    float* out = (float*)d_out;

    const int n = in_sizes[0];
    const int blocks = (n + NBLK - 1) / NBLK;
    pinn_kernel<<<blocks, NBLK, 0, stream>>>(T, W1, b1, W2, b2, W3, b3, W4, b4,
                                             Wo, bo, C1, C2, C3, out, n);
}

// Round 5
// 186.505 us; speedup vs baseline: 6.2660x; 1.5336x over previous
//
#include <hip/hip_runtime.h>

#define NBLK 256

// tanh(x) = 1 - 2/(exp(2x)+1); exp(2x) = exp2(x * 2*log2(e)).
// Overflow -> inf -> rcp(inf)=0 -> 1; underflow -> -1. abs err ~3e-7.
__device__ __forceinline__ float fast_tanh(float x) {
    float e = __builtin_amdgcn_exp2f(x * 2.885390082f);
    return 1.0f - 2.0f * __builtin_amdgcn_rcpf(e + 1.0f);
}

// One hidden layer: (nh, ndh) = tanh-prop of (h, dh) through W[L], b[L].
// sW4: [L][k][jj] float4, linear L*100 + k*5 + jj.  sB4: [L][jj], linear L*5+jj.
template <int L>
__device__ __forceinline__ void layer(const float4* __restrict__ sW4,
                                      const float4* __restrict__ sB4,
                                      const float (&h)[20], const float (&dh)[20],
                                      float (&nh)[20], float (&ndh)[20]) {
#pragma unroll
    for (int jj = 0; jj < 5; ++jj) {
        const float4 b = sB4[L * 5 + jj];
        float a0 = b.x, a1 = b.y, a2 = b.z, a3 = b.w;
        float d0 = 0.f, d1 = 0.f, d2 = 0.f, d3 = 0.f;
#pragma unroll
        for (int k = 0; k < 20; ++k) {
            const float4 ww = sW4[L * 100 + k * 5 + jj];
            const float hk = h[k], dk = dh[k];
            a0 += hk * ww.x; a1 += hk * ww.y; a2 += hk * ww.z; a3 += hk * ww.w;
            d0 += dk * ww.x; d1 += dk * ww.y; d2 += dk * ww.z; d3 += dk * ww.w;
        }
        const float e0 = fast_tanh(a0), e1 = fast_tanh(a1),
                    e2 = fast_tanh(a2), e3 = fast_tanh(a3);
        nh[jj * 4 + 0] = e0; nh[jj * 4 + 1] = e1;
        nh[jj * 4 + 2] = e2; nh[jj * 4 + 3] = e3;
        ndh[jj * 4 + 0] = (1.0f - e0 * e0) * d0;
        ndh[jj * 4 + 1] = (1.0f - e1 * e1) * d1;
        ndh[jj * 4 + 2] = (1.0f - e2 * e2) * d2;
        ndh[jj * 4 + 3] = (1.0f - e3 * e3) * d3;
    }
}

// Single-arg launch_bounds ONLY. Any explicit min-waves-per-EU hint forced a
// sub-footprint VGPR budget and spilled h/dh to scratch:
//   (256,6) -> 40 VGPR, 4.3 GB HBM, 1106 us (R3)
//   (256,4) -> 64 VGPR, 0.9 GB HBM,  216 us (R4)
//   (256)   -> 84 VGPR, no spill,    113 us (R1, rolled variant)
__global__ __launch_bounds__(NBLK) void pinn_kernel(
    const float* __restrict__ T,
    const float* __restrict__ W1, const float* __restrict__ b1,
    const float* __restrict__ W2, const float* __restrict__ b2,
    const float* __restrict__ W3, const float* __restrict__ b3,
    const float* __restrict__ W4, const float* __restrict__ b4,
    const float* __restrict__ Wo, const float* __restrict__ bo,
    const float* __restrict__ C1, const float* __restrict__ C2, const float* __restrict__ C3,
    float* __restrict__ out, int n)
{
    __shared__ float4 sW4[300];    // W2,W3,W4: [L][k][jj]
    __shared__ float4 sB4[15];     // b2,b3,b4: [L][jj]
    __shared__ float4 sW1v[5];     // W1 (20 floats)
    __shared__ float4 sb1v[5];     // b1
    __shared__ float4 sWoT4[15];   // Wo transposed: [o][k] 3x20
    __shared__ float  sbo[3];

    const int tid = threadIdx.x;
    // ---- staging: grid-stride so ALL 300 float4s are covered by 256 threads ----
    for (int v = tid; v < 300; v += NBLK) {
        float4 val;
        if (v < 100)      val = ((const float4*)W2)[v];
        else if (v < 200) val = ((const float4*)W3)[v - 100];
        else              val = ((const float4*)W4)[v - 200];
        sW4[v] = val;
    }
    if (tid < 5) {
        sB4[tid]      = ((const float4*)b2)[tid];
        sB4[5 + tid]  = ((const float4*)b3)[tid];
        sB4[10 + tid] = ((const float4*)b4)[tid];
        sW1v[tid]     = ((const float4*)W1)[tid];
        sb1v[tid]     = ((const float4*)b1)[tid];
    }
    if (tid < 60) {
        // sWoT[o][k] = Wo[k][o]
        reinterpret_cast<float*>(sWoT4)[(tid % 3) * 20 + (tid / 3)] = Wo[tid];
    }
    if (tid < 3) sbo[tid] = bo[tid];

    const int i = blockIdx.x * NBLK + tid;
    const float t = (i < n) ? T[i] : 0.0f;   // load before barrier to hide latency
    __syncthreads();
    if (i >= n) return;

    float hA[20], dA[20], hB[20], dB[20];

    // ---- layer 1: z = t*W1 + b1, dz = W1 ----
#pragma unroll
    for (int jj = 0; jj < 5; ++jj) {
        const float4 w = sW1v[jj];
        const float4 b = sb1v[jj];
        const float z0 = t * w.x + b.x, z1 = t * w.y + b.y,
                    z2 = t * w.z + b.z, z3 = t * w.w + b.w;
        const float e0 = fast_tanh(z0), e1 = fast_tanh(z1),
                    e2 = fast_tanh(z2), e3 = fast_tanh(z3);
        hA[jj * 4 + 0] = e0; hA[jj * 4 + 1] = e1;
        hA[jj * 4 + 2] = e2; hA[jj * 4 + 3] = e3;
        dA[jj * 4 + 0] = (1.0f - e0 * e0) * w.x;
        dA[jj * 4 + 1] = (1.0f - e1 * e1) * w.y;
        dA[jj * 4 + 2] = (1.0f - e2 * e2) * w.z;
        dA[jj * 4 + 3] = (1.0f - e3 * e3) * w.w;
    }

    // ---- layers 2..4, fully unrolled, alternating register arrays ----
    layer<0>(sW4, sB4, hA, dA, hB, dB);
    layer<1>(sW4, sB4, hB, dB, hA, dA);
    layer<2>(sW4, sB4, hA, dA, hB, dB);

    // ---- output layer ----
    float o[3], dO[3];
#pragma unroll
    for (int j = 0; j < 3; ++j) {
        float a = sbo[j], d = 0.f;
#pragma unroll
        for (int kk = 0; kk < 5; ++kk) {
            const float4 ww = sWoT4[j * 5 + kk];
            const int k = kk * 4;
            a += hB[k] * ww.x + hB[k + 1] * ww.y + hB[k + 2] * ww.z + hB[k + 3] * ww.w;
            d += dB[k] * ww.x + dB[k + 1] * ww.y + dB[k + 2] * ww.z + dB[k + 3] * ww.w;
        }
        o[j] = a; dO[j] = d;
    }

    const float x = o[0], y = o[1], zz = o[2];
    const float dx = dO[0], dy = dO[1], dz = dO[2];
    const float c1 = C1[0], c2 = C2[0], c3 = C3[0];

    const float fx = dx - c1 * (y - x);
    const float fy = dy - x * (c2 - zz) + y;
    const float fz = dz - x * y + c3 * zz;

    float2* po = reinterpret_cast<float2*>(out + (size_t)i * 6);
    po[0] = make_float2(x,  y);
    po[1] = make_float2(zz, fx);
    po[2] = make_float2(fy, fz);
}

extern "C" void kernel_launch(void* const* d_in, const int* in_sizes, int n_in,
                              void* d_out, int out_size, void* d_ws, size_t ws_size,
                              hipStream_t stream) {
    const float* T  = (const float*)d_in[0];
    const float* W1 = (const float*)d_in[1];
    const float* b1 = (const float*)d_in[2];
    const float* W2 = (const float*)d_in[3];
    const float* b2 = (const float*)d_in[4];
    const float* W3 = (const float*)d_in[5];
    const float* b3 = (const float*)d_in[6];
    const float* W4 = (const float*)d_in[7];
    const float* b4 = (const float*)d_in[8];
    const float* Wo = (const float*)d_in[9];
    const float* bo = (const float*)d_in[10];
    const float* C1 = (const float*)d_in[11];
    const float* C2 = (const float*)d_in[12];
    const float* C3 = (const float*)d_in[13];
    float* out = (float*)d_out;

    const int n = in_sizes[0];
    const int blocks = (n + NBLK - 1) / NBLK;
    pinn_kernel<<<blocks, NBLK, 0, stream>>>(T, W1, b1, W2, b2, W3, b3, W4, b4,
                                             Wo, bo, C1, C2, C3, out, n);
}